// Round 12
// baseline (727.886 us; speedup 1.0000x reference)
//
#include <hip/hip_runtime.h>

#define NN 200000
#define NE 400000
#define HD 128
#define NL 3
#define NG 4096
#define BN_EPS 1e-5f

// ---------------- workspace layout (bytes) ----------------
#define OFF_DINV  0UL                  // NN floats
#define OFF_H     800000UL             // NN*HD floats
#define OFF_U     103200000UL          // NN*HD bf16 (51.2 MB used)
#define OFF_ACC   205600000UL          // NN*HD bf16 (holds y = dinv*agg)
#define OFF_POOL  308000000UL          // NG*HD floats (group means)
#define OFF_GSTART 310097152UL         // (NG+1) ints
#define OFF_CSUM  310113540UL          // NL*HD floats
#define OFF_CSQ   310115076UL          // NL*HD floats
#define OFF_SCALE 310116612UL          // HD floats
#define OFF_SHIFT 310117124UL          // HD floats
#define OFF_CNTI  310117636UL          // NN ints (in-degree, excl self)
#define OFF_OFFS  310917636UL          // (NN+1) ints + pad
#define OFF_CUR   311717652UL          // NN ints (fill cursors)
#define OFF_SRCS  312517652UL          // NE ints (CSR sources)
#define OFF_BSUM  314117652UL          // scan partials (256 ints)

#define SCAN_B 196                     // ceil(NN/1024)

typedef __attribute__((ext_vector_type(8))) short v8s;            // 8 bf16 (4 VGPRs)
typedef __attribute__((ext_vector_type(4))) float v4f;            // 4 fp32
typedef __attribute__((ext_vector_type(4))) unsigned short v4u;   // 4 bf16
typedef __attribute__((ext_vector_type(8))) unsigned short v8u;   // 8 bf16

__device__ inline unsigned short f_to_bf_rne(float f) {
    unsigned u = __float_as_uint(f);
    return (unsigned short)((u + 0x7fffu + ((u >> 16) & 1u)) >> 16);
}

__device__ inline v4f bf4_to_f(v4u a) {
    v4f r;
    r[0] = __uint_as_float(((unsigned)a[0]) << 16);
    r[1] = __uint_as_float(((unsigned)a[1]) << 16);
    r[2] = __uint_as_float(((unsigned)a[2]) << 16);
    r[3] = __uint_as_float(((unsigned)a[3]) << 16);
    return r;
}

__global__ void count_deg_i(const int* __restrict__ col, int* __restrict__ cnt) {
    int e = blockIdx.x * blockDim.x + threadIdx.x;
    if (e < NE) atomicAdd(&cnt[col[e]], 1);
}

__global__ void finalize_dinv(const int* __restrict__ cnt, float* __restrict__ dinv) {
    int i = blockIdx.x * blockDim.x + threadIdx.x;
    if (i < NN) dinv[i] = rsqrtf((float)(cnt[i] + 1));   // +1 self-loop
}

// ---- exclusive scan of cnt[NN] -> offs[NN+1] (three phases) ----
__global__ void scan_phase1(const int* __restrict__ cnt, int* __restrict__ bsum) {
    __shared__ int sh[256];
    int b = blockIdx.x, t = threadIdx.x;
    int base = b * 1024 + t * 4;
    int s = 0;
#pragma unroll
    for (int j = 0; j < 4; ++j) if (base + j < NN) s += cnt[base + j];
    sh[t] = s;
    __syncthreads();
    for (int st = 128; st > 0; st >>= 1) {
        if (t < st) sh[t] += sh[t + st];
        __syncthreads();
    }
    if (t == 0) bsum[b] = sh[0];
}

__global__ void scan_phase2(int* __restrict__ bsum, int* __restrict__ offs) {
    if (threadIdx.x == 0) {
        int run = 0;
        for (int i = 0; i < SCAN_B; ++i) { int v = bsum[i]; bsum[i] = run; run += v; }
        offs[NN] = NE;
    }
}

__global__ void scan_phase3(const int* __restrict__ cnt, const int* __restrict__ bsum,
                            int* __restrict__ offs) {
    __shared__ int sh[256];
    int b = blockIdx.x, t = threadIdx.x;
    int base = b * 1024 + t * 4;
    int v[4];
    int s = 0;
#pragma unroll
    for (int j = 0; j < 4; ++j) { v[j] = (base + j < NN) ? cnt[base + j] : 0; s += v[j]; }
    sh[t] = s;
    __syncthreads();
    for (int st = 1; st < 256; st <<= 1) {
        int x = (t >= st) ? sh[t - st] : 0;
        __syncthreads();
        sh[t] += x;
        __syncthreads();
    }
    int run = sh[t] - s + bsum[b];   // exclusive prefix for this thread's range
#pragma unroll
    for (int j = 0; j < 4; ++j) {
        if (base + j < NN) { offs[base + j] = run; run += v[j]; }
    }
}

__global__ void fill_csr(const int* __restrict__ row, const int* __restrict__ col,
                         const int* __restrict__ offs, int* __restrict__ cur,
                         int* __restrict__ srcs) {
    int e = blockIdx.x * blockDim.x + threadIdx.x;
    if (e >= NE) return;
    int c = col[e];
    int p = offs[c] + atomicAdd(&cur[c], 1);
    srcs[p] = row[e];
}

// float -> (bf16 hi RNE, bf16 lo RNE of exact residual)
__device__ inline void cvt_split(float f, short& hi, short& lo) {
    unsigned u = __float_as_uint(f);
    unsigned rh = (u + 0x7fffu + ((u >> 16) & 1u)) >> 16;
    hi = (short)rh;
    float fh = __uint_as_float(rh << 16);
    float d = f - fh;                      // exact in fp32
    unsigned u2 = __float_as_uint(d);
    unsigned rl = (u2 + 0x7fffu + ((u2 >> 16) & 1u)) >> 16;
    lo = (short)rl;
}

// O = A @ W (+bias) (*dinv), via MFMA 16x16x32 bf16 with bf16x3 split.
// Block: 512 thr = 8 waves; each wave one 16-row strip per task; grid-stride.
// Register double-buffer: next task's A-rows prefetched during current task's
// cvt/MFMA/epilogue (LDS is full with W; ~8 extra loads in flight per wave).
// FUSE_BN: A-row construction applies h += relu(y*scale+shift) in-place.
// OUT_BF16: output rounded RNE to bf16 (for u).
#define GEMM_BLOCKS 512
template <bool ADD_BIAS, bool SCALE_DINV, bool FUSE_BN, bool OUT_BF16>
__launch_bounds__(512, 4)
__global__ void gemm_mfma(float* __restrict__ A, const float* __restrict__ W,
                          const float* __restrict__ bias, const float* __restrict__ dinv,
                          const float* __restrict__ bnscale, const float* __restrict__ bnshift,
                          const unsigned short* __restrict__ bnacc,
                          void* __restrict__ Ov, int M) {
    __shared__ short Wh[HD * HD];   // Wt[c][k] hi, granule G stored at G^(c&7)
    __shared__ short Wlo[HD * HD];  // Wt[c][k] lo

    {   // stage + convert + transpose + swizzle W (512 thr: 1 col x 4 granules each)
        int c = threadIdx.x >> 2;
        int quarter = threadIdx.x & 3;
#pragma unroll
        for (int g8 = 0; g8 < 4; ++g8) {
            int G = quarter * 4 + g8;
            v8s h8, l8;
#pragma unroll
            for (int j = 0; j < 8; ++j) {
                float f = W[(G * 8 + j) * HD + c];
                short hi, lo;
                cvt_split(f, hi, lo);
                h8[j] = hi; l8[j] = lo;
            }
            int off = c * HD + (G ^ (c & 7)) * 8;
            *(v8s*)&Wh[off] = h8;
            *(v8s*)&Wlo[off] = l8;
        }
    }
    __syncthreads();

    int wave = threadIdx.x >> 6;
    int lane = threadIdx.x & 63;
    int m = lane & 15;        // A-row / B-col lane index
    int q = lane >> 4;        // quad

    const float4* sc4 = (const float4*)bnscale;
    const float4* sf4 = (const float4*)bnshift;

    int task = blockIdx.x;
    float4 xc[4][2];
    {   // preload current task's A rows (clamped; unused lanes guarded later)
        int rbase = task * 128 + wave * 16;
        int rrow = min(rbase + m, M - 1);
        const float* Ar = A + (size_t)rrow * HD;
#pragma unroll
        for (int kc = 0; kc < 4; ++kc) {
            xc[kc][0] = *(const float4*)(Ar + kc * 32 + q * 8);
            xc[kc][1] = *(const float4*)(Ar + kc * 32 + q * 8 + 4);
        }
    }

    for (; task * 128 < M; task += GEMM_BLOCKS) {
        int rbase = task * 128 + wave * 16;
        int nxt = task + GEMM_BLOCKS;

        float4 xn[4][2];
        if (nxt * 128 < M) {   // issue next task's loads NOW (hidden by compute)
            int nrb = nxt * 128 + wave * 16;
            int nrow = min(nrb + m, M - 1);
            const float* An = A + (size_t)nrow * HD;
#pragma unroll
            for (int kc = 0; kc < 4; ++kc) {
                xn[kc][0] = *(const float4*)(An + kc * 32 + q * 8);
                xn[kc][1] = *(const float4*)(An + kc * 32 + q * 8 + 4);
            }
        }

        if (rbase < M) {       // strips 16-aligned, M%16==0
            float* Ar = A + (size_t)(rbase + m) * HD;

            v8s ah[4], al[4];
#pragma unroll
            for (int kc = 0; kc < 4; ++kc) {
                float4 x0 = xc[kc][0];
                float4 x1 = xc[kc][1];
                if (FUSE_BN) {
                    v8u y8 = *(const v8u*)(bnacc + (size_t)(rbase + m) * HD + kc * 32 + q * 8);
                    v4f y0 = bf4_to_f((v4u){y8[0], y8[1], y8[2], y8[3]});
                    v4f y1 = bf4_to_f((v4u){y8[4], y8[5], y8[6], y8[7]});
                    float4 s0 = sc4[kc * 8 + q * 2], s1 = sc4[kc * 8 + q * 2 + 1];
                    float4 f0 = sf4[kc * 8 + q * 2], f1 = sf4[kc * 8 + q * 2 + 1];
                    x0.x += fmaxf(fmaf(y0[0], s0.x, f0.x), 0.f);
                    x0.y += fmaxf(fmaf(y0[1], s0.y, f0.y), 0.f);
                    x0.z += fmaxf(fmaf(y0[2], s0.z, f0.z), 0.f);
                    x0.w += fmaxf(fmaf(y0[3], s0.w, f0.w), 0.f);
                    x1.x += fmaxf(fmaf(y1[0], s1.x, f1.x), 0.f);
                    x1.y += fmaxf(fmaf(y1[1], s1.y, f1.y), 0.f);
                    x1.z += fmaxf(fmaf(y1[2], s1.z, f1.z), 0.f);
                    x1.w += fmaxf(fmaf(y1[3], s1.w, f1.w), 0.f);
                    *(float4*)(Ar + kc * 32 + q * 8) = x0;      // h update in-place
                    *(float4*)(Ar + kc * 32 + q * 8 + 4) = x1;
                }
                float xs[8] = {x0.x, x0.y, x0.z, x0.w, x1.x, x1.y, x1.z, x1.w};
                v8s h8, l8;
#pragma unroll
                for (int j = 0; j < 8; ++j) {
                    short hi, lo;
                    cvt_split(xs[j], hi, lo);
                    h8[j] = hi; l8[j] = lo;
                }
                ah[kc] = h8; al[kc] = l8;
            }

            v4f acc[8];
#pragma unroll
            for (int ct = 0; ct < 8; ++ct) acc[ct] = (v4f){0.f, 0.f, 0.f, 0.f};

#pragma unroll
            for (int kc = 0; kc < 4; ++kc) {
#pragma unroll
                for (int ct = 0; ct < 8; ++ct) {
                    int c = ct * 16 + m;
                    int off = c * HD + (((kc * 4 + q) ^ (c & 7)) * 8);
                    v8s bh = *(const v8s*)&Wh[off];
                    v8s bl = *(const v8s*)&Wlo[off];
                    acc[ct] = __builtin_amdgcn_mfma_f32_16x16x32_bf16(ah[kc], bh, acc[ct], 0, 0, 0);
                    acc[ct] = __builtin_amdgcn_mfma_f32_16x16x32_bf16(al[kc], bh, acc[ct], 0, 0, 0);
                    acc[ct] = __builtin_amdgcn_mfma_f32_16x16x32_bf16(ah[kc], bl, acc[ct], 0, 0, 0);
                }
            }

            // epilogue: D lane mapping col=lane&15, row=(lane>>4)*4+reg
            float dv[4];
#pragma unroll
            for (int reg = 0; reg < 4; ++reg)
                dv[reg] = SCALE_DINV ? dinv[rbase + q * 4 + reg] : 1.0f;
#pragma unroll
            for (int ct = 0; ct < 8; ++ct) {
                int colb = ct * 16 + m;
                float bb = ADD_BIAS ? bias[colb] : 0.0f;
#pragma unroll
                for (int reg = 0; reg < 4; ++reg) {
                    int rr = rbase + q * 4 + reg;
                    float v = acc[ct][reg] + bb;
                    if (SCALE_DINV) v *= dv[reg];
                    if (OUT_BF16) {
                        ((unsigned short*)Ov)[(size_t)rr * HD + colb] = f_to_bf_rne(v);
                    } else {
                        ((float*)Ov)[(size_t)rr * HD + colb] = v;
                    }
                }
            }
        }

#pragma unroll
        for (int kc = 0; kc < 4; ++kc) {
            xc[kc][0] = xn[kc][0];
            xc[kc][1] = xn[kc][1];
        }
    }
}

// acc[i] = y_i = dinv[i]*(u[i] + sum_{e: col=i} u[src[e]]), stored bf16.
// 16 lanes per node (v8u = 16B/lane): 4 node streams per wave + x2 edge
// unroll -> more independent random row-reads in flight per wave.
// BN col stats computed on the ROUNDED values (matches what's applied).
#define GATHER_BLOCKS 1024
__global__ void gather_bn(const int* __restrict__ offs, const int* __restrict__ srcs,
                          const unsigned short* __restrict__ u, const float* __restrict__ dinv,
                          unsigned short* __restrict__ acc,
                          float* __restrict__ colsum, float* __restrict__ colsumsq) {
    const v8u* u8p = (const v8u*)u;    // 16 x v8u per row
    v8u* acc8 = (v8u*)acc;
    int n = threadIdx.x >> 4;     // node slot 0..15
    int q = threadIdx.x & 15;     // 8-col group within row
    v4f t1a = (v4f){0.f, 0.f, 0.f, 0.f}, t1b = t1a;
    v4f t2a = t1a, t2b = t1a;

    for (int node = blockIdx.x * 16 + n; node < NN; node += GATHER_BLOCKS * 16) {
        v8u s8 = u8p[(size_t)node * 16 + q];   // self-loop seed
        v4f sa = bf4_to_f((v4u){s8[0], s8[1], s8[2], s8[3]});
        v4f sb = bf4_to_f((v4u){s8[4], s8[5], s8[6], s8[7]});
        int k = offs[node];
        int k1 = offs[node + 1];
        for (; k + 2 <= k1; k += 2) {
            int s0 = srcs[k], s1 = srcs[k + 1];
            v8u a8 = u8p[(size_t)s0 * 16 + q];
            v8u b8 = u8p[(size_t)s1 * 16 + q];
            sa += bf4_to_f((v4u){a8[0], a8[1], a8[2], a8[3]});
            sb += bf4_to_f((v4u){a8[4], a8[5], a8[6], a8[7]});
            sa += bf4_to_f((v4u){b8[0], b8[1], b8[2], b8[3]});
            sb += bf4_to_f((v4u){b8[4], b8[5], b8[6], b8[7]});
        }
        if (k < k1) {
            v8u a8 = u8p[(size_t)srcs[k] * 16 + q];
            sa += bf4_to_f((v4u){a8[0], a8[1], a8[2], a8[3]});
            sb += bf4_to_f((v4u){a8[4], a8[5], a8[6], a8[7]});
        }
        float d = dinv[node];
        sa *= d; sb *= d;
        v8u o8;
        o8[0] = f_to_bf_rne(sa[0]); o8[1] = f_to_bf_rne(sa[1]);
        o8[2] = f_to_bf_rne(sa[2]); o8[3] = f_to_bf_rne(sa[3]);
        o8[4] = f_to_bf_rne(sb[0]); o8[5] = f_to_bf_rne(sb[1]);
        o8[6] = f_to_bf_rne(sb[2]); o8[7] = f_to_bf_rne(sb[3]);
        acc8[(size_t)node * 16 + q] = o8;
        v4f ra = bf4_to_f((v4u){o8[0], o8[1], o8[2], o8[3]});   // stats on rounded y
        v4f rb = bf4_to_f((v4u){o8[4], o8[5], o8[6], o8[7]});
        t1a += ra; t1b += rb;
        t2a += ra * ra; t2b += rb * rb;
    }

    __shared__ float sh1[16][HD];
    __shared__ float sh2[16][HD];
    *(v4f*)&sh1[n][q * 8] = t1a;
    *(v4f*)&sh1[n][q * 8 + 4] = t1b;
    *(v4f*)&sh2[n][q * 8] = t2a;
    *(v4f*)&sh2[n][q * 8 + 4] = t2b;
    __syncthreads();
    if (threadIdx.x < HD) {
        int c = threadIdx.x;
        float a1 = 0.f, a2 = 0.f;
#pragma unroll
        for (int i = 0; i < 16; ++i) { a1 += sh1[i][c]; a2 += sh2[i][c]; }
        atomicAdd(&colsum[c], a1);
        atomicAdd(&colsumsq[c], a2);
    }
}

__global__ void bn_finalize(const float* __restrict__ colsum, const float* __restrict__ colsumsq,
                            const float* __restrict__ gamma, const float* __restrict__ beta,
                            float* __restrict__ scale, float* __restrict__ shift) {
    int c = threadIdx.x;
    float invn = 1.0f / (float)NN;
    float m = colsum[c] * invn;
    float v = colsumsq[c] * invn - m * m;
    float sc = gamma[c] * rsqrtf(v + BN_EPS);
    scale[c] = sc;
    shift[c] = beta[c] - m * sc;
}

// gstart[g] = first node index with batch >= g (batch is sorted ascending).
__global__ void group_bounds(const int* __restrict__ batch, int* __restrict__ gstart) {
    int g = blockIdx.x * blockDim.x + threadIdx.x;
    if (g > NG) return;
    if (g == NG) { gstart[NG] = NN; return; }
    int lo = 0, hi = NN;
    while (lo < hi) {
        int mid = (lo + hi) >> 1;
        if (batch[mid] < g) lo = mid + 1; else hi = mid;
    }
    gstart[g] = lo;
}

// Fused last-layer bn_apply + mean-pool: pool[g][c] = mean(h + relu(y*scale+shift)).
__launch_bounds__(128)
__global__ void pool_bn_mean(const unsigned short* __restrict__ acc, const float* __restrict__ h,
                             const float* __restrict__ scale, const float* __restrict__ shift,
                             const int* __restrict__ gstart, float* __restrict__ pool) {
    int g = blockIdx.x;
    int c = threadIdx.x;
    float sc = scale[c], sf = shift[c];
    int s = gstart[g], e = gstart[g + 1];
    float a = 0.f;
    for (int r = s; r < e; ++r) {
        float yv = __uint_as_float(((unsigned)acc[(size_t)r * HD + c]) << 16);
        float y = fmaxf(fmaf(yv, sc, sf), 0.f);
        a += h[(size_t)r * HD + c] + y;
    }
    float ic = 1.0f / fmaxf((float)(e - s), 1.0f);
    pool[(size_t)g * HD + c] = a * ic;
}

__launch_bounds__(128)
__global__ void out_gemm(const float* __restrict__ pool,
                         const float* __restrict__ Wout, const float* __restrict__ bout,
                         float* __restrict__ out) {
    __shared__ float hb[HD];
    int g = blockIdx.x;
    int c = threadIdx.x;
    hb[c] = pool[(size_t)g * HD + c];
    __syncthreads();
    float o = bout[c];
#pragma unroll 8
    for (int k = 0; k < HD; ++k) o = fmaf(hb[k], Wout[k * HD + c], o);
    out[(size_t)g * HD + c] = o;
}

extern "C" void kernel_launch(void* const* d_in, const int* in_sizes, int n_in,
                              void* d_out, int out_size, void* d_ws, size_t ws_size,
                              hipStream_t stream) {
    const float* x      = (const float*)d_in[0];
    const float* W_in   = (const float*)d_in[1];
    const float* b_in   = (const float*)d_in[2];
    const float* W_conv = (const float*)d_in[3];
    // d_in[4] = b_conv — cancels exactly inside BatchNorm (mean shift only), unused.
    const float* gamma  = (const float*)d_in[5];
    const float* beta   = (const float*)d_in[6];
    const float* W_out  = (const float*)d_in[7];
    const float* b_out  = (const float*)d_in[8];
    const int*   edge   = (const int*)d_in[9];
    const int*   batch  = (const int*)d_in[10];
    float* out = (float*)d_out;

    char* ws = (char*)d_ws;
    float* dinv   = (float*)(ws + OFF_DINV);
    float* h      = (float*)(ws + OFF_H);
    unsigned short* u   = (unsigned short*)(ws + OFF_U);
    unsigned short* acc = (unsigned short*)(ws + OFF_ACC);
    float* pool   = (float*)(ws + OFF_POOL);
    int*   gstart = (int*)(ws + OFF_GSTART);
    float* csum   = (float*)(ws + OFF_CSUM);
    float* csq    = (float*)(ws + OFF_CSQ);
    float* scale  = (float*)(ws + OFF_SCALE);
    float* shift  = (float*)(ws + OFF_SHIFT);
    int*   cnti   = (int*)(ws + OFF_CNTI);
    int*   offs   = (int*)(ws + OFF_OFFS);
    int*   cur    = (int*)(ws + OFF_CUR);
    int*   srcs   = (int*)(ws + OFF_SRCS);
    int*   bsum   = (int*)(ws + OFF_BSUM);

    const int* row = edge;        // sources
    const int* col = edge + NE;   // targets

    // zero: BN stats region, and cnti/cur region
    hipMemsetAsync(ws + OFF_CSUM, 0, OFF_SHIFT + 512 - OFF_CSUM, stream);
    hipMemsetAsync(ws + OFF_CNTI, 0, OFF_SRCS - OFF_CNTI, stream);

    // CSR build + dinv + group bounds
    count_deg_i<<<(NE + 255) / 256, 256, 0, stream>>>(col, cnti);
    finalize_dinv<<<(NN + 255) / 256, 256, 0, stream>>>(cnti, dinv);
    scan_phase1<<<SCAN_B, 256, 0, stream>>>(cnti, bsum);
    scan_phase2<<<1, 64, 0, stream>>>(bsum, offs);
    scan_phase3<<<SCAN_B, 256, 0, stream>>>(cnti, bsum, offs);
    fill_csr<<<(NE + 255) / 256, 256, 0, stream>>>(row, col, offs, cur, srcs);
    group_bounds<<<(NG + 256) / 256, 256, 0, stream>>>(batch, gstart);

    // h = x @ W_in + b_in  (fp32 out)
    gemm_mfma<true, false, false, false><<<GEMM_BLOCKS, 512, 0, stream>>>(
        (float*)x, W_in, b_in, nullptr, nullptr, nullptr, nullptr, h, NN);

    for (int l = 0; l < NL; ++l) {
        // u = (h @ W_conv[l]) * dinv  (bf16 out); for l>0 the A-load fuses the
        // previous layer's bn_apply (h += relu(acc*scale+shift), in-place).
        if (l == 0) {
            gemm_mfma<false, true, false, true><<<GEMM_BLOCKS, 512, 0, stream>>>(
                h, W_conv + (size_t)l * HD * HD, nullptr, dinv,
                nullptr, nullptr, nullptr, u, NN);
        } else {
            gemm_mfma<false, true, true, true><<<GEMM_BLOCKS, 512, 0, stream>>>(
                h, W_conv + (size_t)l * HD * HD, nullptr, dinv,
                scale, shift, acc, u, NN);
        }
        gather_bn<<<GATHER_BLOCKS, 256, 0, stream>>>(
            offs, srcs, u, dinv, acc, csum + l * HD, csq + l * HD);
        bn_finalize<<<1, HD, 0, stream>>>(
            csum + l * HD, csq + l * HD, gamma + l * HD, beta + l * HD, scale, shift);
    }

    // fused: pool[g] = mean(h + relu(acc*scale+shift)) over group rows
    pool_bn_mean<<<NG, 128, 0, stream>>>(acc, h, scale, shift, gstart, pool);
    out_gemm<<<NG, 128, 0, stream>>>(pool, W_out, b_out, out);
}

// Round 13
// 600.863 us; speedup vs baseline: 1.2114x; 1.2114x over previous
//
#include <hip/hip_runtime.h>

#define NN 200000
#define NE 400000
#define HD 128
#define NL 3
#define NG 4096
#define BN_EPS 1e-5f

// ---------------- workspace layout (bytes) ----------------
#define OFF_DINV  0UL                  // NN floats
#define OFF_H     800000UL             // NN*HD bf16 (51.2 MB used)
#define OFF_U     103200000UL          // NN*HD bf16 (51.2 MB used)
#define OFF_ACC   205600000UL          // NN*HD bf16 (holds y = dinv*agg)
#define OFF_POOL  308000000UL          // NG*HD floats (group means)
#define OFF_GSTART 310097152UL         // (NG+1) ints
#define OFF_CSUM  310113540UL          // NL*HD floats
#define OFF_CSQ   310115076UL          // NL*HD floats
#define OFF_SCALE 310116612UL          // HD floats
#define OFF_SHIFT 310117124UL          // HD floats
#define OFF_CNTI  310117636UL          // NN ints (in-degree, excl self)
#define OFF_OFFS  310917636UL          // (NN+1) ints + pad
#define OFF_CUR   311717652UL          // NN ints (fill cursors)
#define OFF_SRCS  312517652UL          // NE ints (CSR sources)
#define OFF_BSUM  314117652UL          // scan partials (256 ints)

#define SCAN_B 196                     // ceil(NN/1024)

typedef __attribute__((ext_vector_type(8))) short v8s;            // 8 bf16 (4 VGPRs)
typedef __attribute__((ext_vector_type(4))) float v4f;            // 4 fp32
typedef __attribute__((ext_vector_type(4))) unsigned short v4u;   // 4 bf16
typedef __attribute__((ext_vector_type(8))) unsigned short v8u;   // 8 bf16

__device__ inline unsigned short f_to_bf_rne(float f) {
    unsigned u = __float_as_uint(f);
    return (unsigned short)((u + 0x7fffu + ((u >> 16) & 1u)) >> 16);
}

__device__ inline float bf_to_f(unsigned short a) {
    return __uint_as_float(((unsigned)a) << 16);
}

__device__ inline v4f bf4_to_f(v4u a) {
    v4f r;
    r[0] = bf_to_f(a[0]); r[1] = bf_to_f(a[1]);
    r[2] = bf_to_f(a[2]); r[3] = bf_to_f(a[3]);
    return r;
}

__global__ void count_deg_i(const int* __restrict__ col, int* __restrict__ cnt) {
    int e = blockIdx.x * blockDim.x + threadIdx.x;
    if (e < NE) atomicAdd(&cnt[col[e]], 1);
}

__global__ void finalize_dinv(const int* __restrict__ cnt, float* __restrict__ dinv) {
    int i = blockIdx.x * blockDim.x + threadIdx.x;
    if (i < NN) dinv[i] = rsqrtf((float)(cnt[i] + 1));   // +1 self-loop
}

// ---- exclusive scan of cnt[NN] -> offs[NN+1] (three phases) ----
__global__ void scan_phase1(const int* __restrict__ cnt, int* __restrict__ bsum) {
    __shared__ int sh[256];
    int b = blockIdx.x, t = threadIdx.x;
    int base = b * 1024 + t * 4;
    int s = 0;
#pragma unroll
    for (int j = 0; j < 4; ++j) if (base + j < NN) s += cnt[base + j];
    sh[t] = s;
    __syncthreads();
    for (int st = 128; st > 0; st >>= 1) {
        if (t < st) sh[t] += sh[t + st];
        __syncthreads();
    }
    if (t == 0) bsum[b] = sh[0];
}

__global__ void scan_phase2(int* __restrict__ bsum, int* __restrict__ offs) {
    if (threadIdx.x == 0) {
        int run = 0;
        for (int i = 0; i < SCAN_B; ++i) { int v = bsum[i]; bsum[i] = run; run += v; }
        offs[NN] = NE;
    }
}

__global__ void scan_phase3(const int* __restrict__ cnt, const int* __restrict__ bsum,
                            int* __restrict__ offs) {
    __shared__ int sh[256];
    int b = blockIdx.x, t = threadIdx.x;
    int base = b * 1024 + t * 4;
    int v[4];
    int s = 0;
#pragma unroll
    for (int j = 0; j < 4; ++j) { v[j] = (base + j < NN) ? cnt[base + j] : 0; s += v[j]; }
    sh[t] = s;
    __syncthreads();
    for (int st = 1; st < 256; st <<= 1) {
        int x = (t >= st) ? sh[t - st] : 0;
        __syncthreads();
        sh[t] += x;
        __syncthreads();
    }
    int run = sh[t] - s + bsum[b];   // exclusive prefix for this thread's range
#pragma unroll
    for (int j = 0; j < 4; ++j) {
        if (base + j < NN) { offs[base + j] = run; run += v[j]; }
    }
}

__global__ void fill_csr(const int* __restrict__ row, const int* __restrict__ col,
                         const int* __restrict__ offs, int* __restrict__ cur,
                         int* __restrict__ srcs) {
    int e = blockIdx.x * blockDim.x + threadIdx.x;
    if (e >= NE) return;
    int c = col[e];
    int p = offs[c] + atomicAdd(&cur[c], 1);
    srcs[p] = row[e];
}

// float -> (bf16 hi RNE, bf16 lo RNE of exact residual)
__device__ inline void cvt_split(float f, short& hi, short& lo) {
    unsigned u = __float_as_uint(f);
    unsigned rh = (u + 0x7fffu + ((u >> 16) & 1u)) >> 16;
    hi = (short)rh;
    float fh = __uint_as_float(rh << 16);
    float d = f - fh;                      // exact in fp32
    unsigned u2 = __float_as_uint(d);
    unsigned rl = (u2 + 0x7fffu + ((u2 >> 16) & 1u)) >> 16;
    lo = (short)rl;
}

// O = A @ W (+bias) (*dinv) -> bf16, via MFMA 16x16x32 bf16.
// W split hi/lo bf16 in LDS (64 KB, transposed + XOR-swizzled).
// A_BF16=false (x input): A fp32, bf16x3 split -> 3 MFMA terms.
// A_BF16=true (h): A is bf16 EXACTLY -> no cvt_split, 2 MFMA terms (a*bh + a*bl).
// FUSE_BN (requires A_BF16): A-load computes h' = bf16(h + relu(y*sc+sf)),
// stores h' in place, and uses h' as the A fragment (consistent).
// Block: 512 thr = 8 waves, one 16-row strip per wave per task; grid-stride.
#define GEMM_BLOCKS 512
template <bool ADD_BIAS, bool SCALE_DINV, bool FUSE_BN, bool A_BF16>
__launch_bounds__(512, 4)
__global__ void gemm_mfma(void* __restrict__ Av, const float* __restrict__ W,
                          const float* __restrict__ bias, const float* __restrict__ dinv,
                          const float* __restrict__ bnscale, const float* __restrict__ bnshift,
                          const unsigned short* __restrict__ bnacc,
                          unsigned short* __restrict__ O, int M) {
    __shared__ short Wh[HD * HD];   // Wt[c][k] hi, granule G stored at G^(c&7)
    __shared__ short Wlo[HD * HD];  // Wt[c][k] lo

    {   // stage + convert + transpose + swizzle W (512 thr: 1 col x 4 granules each)
        int c = threadIdx.x >> 2;
        int quarter = threadIdx.x & 3;
#pragma unroll
        for (int g8 = 0; g8 < 4; ++g8) {
            int G = quarter * 4 + g8;
            v8s h8, l8;
#pragma unroll
            for (int j = 0; j < 8; ++j) {
                float f = W[(G * 8 + j) * HD + c];
                short hi, lo;
                cvt_split(f, hi, lo);
                h8[j] = hi; l8[j] = lo;
            }
            int off = c * HD + (G ^ (c & 7)) * 8;
            *(v8s*)&Wh[off] = h8;
            *(v8s*)&Wlo[off] = l8;
        }
    }
    __syncthreads();

    int wave = threadIdx.x >> 6;
    int lane = threadIdx.x & 63;
    int m = lane & 15;        // A-row / B-col lane index
    int q = lane >> 4;        // quad

    for (int task = blockIdx.x; task * 128 < M; task += GEMM_BLOCKS) {
        int rbase = task * 128 + wave * 16;
        if (rbase >= M) continue;     // strips 16-aligned, M%16==0

        v8s ah[4], al[4];
#pragma unroll
        for (int kc = 0; kc < 4; ++kc) {
            if (!A_BF16) {
                const float* Ar = (const float*)Av + (size_t)(rbase + m) * HD;
                float4 x0 = *(const float4*)(Ar + kc * 32 + q * 8);
                float4 x1 = *(const float4*)(Ar + kc * 32 + q * 8 + 4);
                float xs[8] = {x0.x, x0.y, x0.z, x0.w, x1.x, x1.y, x1.z, x1.w};
                v8s h8, l8;
#pragma unroll
                for (int j = 0; j < 8; ++j) {
                    short hi, lo;
                    cvt_split(xs[j], hi, lo);
                    h8[j] = hi; l8[j] = lo;
                }
                ah[kc] = h8; al[kc] = l8;
            } else {
                unsigned short* Ar = (unsigned short*)Av + (size_t)(rbase + m) * HD;
                v8u a8 = *(const v8u*)(Ar + kc * 32 + q * 8);
                if (FUSE_BN) {
                    v8u y8 = *(const v8u*)(bnacc + (size_t)(rbase + m) * HD + kc * 32 + q * 8);
                    const float* scp = bnscale + kc * 32 + q * 8;
                    const float* sfp = bnshift + kc * 32 + q * 8;
                    v8u o8;
#pragma unroll
                    for (int j = 0; j < 8; ++j) {
                        float hn = bf_to_f(a8[j]) +
                                   fmaxf(fmaf(bf_to_f(y8[j]), scp[j], sfp[j]), 0.f);
                        o8[j] = f_to_bf_rne(hn);
                    }
                    *(v8u*)(Ar + kc * 32 + q * 8) = o8;   // h update in-place
                    a8 = o8;
                }
                ah[kc] = (v8s)a8;
            }
        }

        v4f acc[8];
#pragma unroll
        for (int ct = 0; ct < 8; ++ct) acc[ct] = (v4f){0.f, 0.f, 0.f, 0.f};

#pragma unroll
        for (int kc = 0; kc < 4; ++kc) {
#pragma unroll
            for (int ct = 0; ct < 8; ++ct) {
                int c = ct * 16 + m;
                int off = c * HD + (((kc * 4 + q) ^ (c & 7)) * 8);
                v8s bh = *(const v8s*)&Wh[off];
                v8s bl = *(const v8s*)&Wlo[off];
                acc[ct] = __builtin_amdgcn_mfma_f32_16x16x32_bf16(ah[kc], bh, acc[ct], 0, 0, 0);
                if (!A_BF16)
                    acc[ct] = __builtin_amdgcn_mfma_f32_16x16x32_bf16(al[kc], bh, acc[ct], 0, 0, 0);
                acc[ct] = __builtin_amdgcn_mfma_f32_16x16x32_bf16(ah[kc], bl, acc[ct], 0, 0, 0);
            }
        }

        // epilogue: D lane mapping col=lane&15, row=(lane>>4)*4+reg
        float dv[4];
#pragma unroll
        for (int reg = 0; reg < 4; ++reg)
            dv[reg] = SCALE_DINV ? dinv[rbase + q * 4 + reg] : 1.0f;
#pragma unroll
        for (int ct = 0; ct < 8; ++ct) {
            int colb = ct * 16 + m;
            float bb = ADD_BIAS ? bias[colb] : 0.0f;
#pragma unroll
            for (int reg = 0; reg < 4; ++reg) {
                int rr = rbase + q * 4 + reg;
                float v = acc[ct][reg] + bb;
                if (SCALE_DINV) v *= dv[reg];
                O[(size_t)rr * HD + colb] = f_to_bf_rne(v);
            }
        }
    }
}

// acc[i] = y_i = dinv[i]*(u[i] + sum_{e: col=i} u[src[e]]), stored bf16.
// 16 lanes per node (v8u = 16B/lane): 4 node streams per wave + x2 edge
// unroll -> more independent random row-reads in flight per wave.
// BN col stats computed on the ROUNDED values (matches what's applied).
#define GATHER_BLOCKS 1024
__global__ void gather_bn(const int* __restrict__ offs, const int* __restrict__ srcs,
                          const unsigned short* __restrict__ u, const float* __restrict__ dinv,
                          unsigned short* __restrict__ acc,
                          float* __restrict__ colsum, float* __restrict__ colsumsq) {
    const v8u* u8p = (const v8u*)u;    // 16 x v8u per row
    v8u* acc8 = (v8u*)acc;
    int n = threadIdx.x >> 4;     // node slot 0..15
    int q = threadIdx.x & 15;     // 8-col group within row
    v4f t1a = (v4f){0.f, 0.f, 0.f, 0.f}, t1b = t1a;
    v4f t2a = t1a, t2b = t1a;

    for (int node = blockIdx.x * 16 + n; node < NN; node += GATHER_BLOCKS * 16) {
        v8u s8 = u8p[(size_t)node * 16 + q];   // self-loop seed
        v4f sa = bf4_to_f((v4u){s8[0], s8[1], s8[2], s8[3]});
        v4f sb = bf4_to_f((v4u){s8[4], s8[5], s8[6], s8[7]});
        int k = offs[node];
        int k1 = offs[node + 1];
        for (; k + 2 <= k1; k += 2) {
            int s0 = srcs[k], s1 = srcs[k + 1];
            v8u a8 = u8p[(size_t)s0 * 16 + q];
            v8u b8 = u8p[(size_t)s1 * 16 + q];
            sa += bf4_to_f((v4u){a8[0], a8[1], a8[2], a8[3]});
            sb += bf4_to_f((v4u){a8[4], a8[5], a8[6], a8[7]});
            sa += bf4_to_f((v4u){b8[0], b8[1], b8[2], b8[3]});
            sb += bf4_to_f((v4u){b8[4], b8[5], b8[6], b8[7]});
        }
        if (k < k1) {
            v8u a8 = u8p[(size_t)srcs[k] * 16 + q];
            sa += bf4_to_f((v4u){a8[0], a8[1], a8[2], a8[3]});
            sb += bf4_to_f((v4u){a8[4], a8[5], a8[6], a8[7]});
        }
        float d = dinv[node];
        sa *= d; sb *= d;
        v8u o8;
        o8[0] = f_to_bf_rne(sa[0]); o8[1] = f_to_bf_rne(sa[1]);
        o8[2] = f_to_bf_rne(sa[2]); o8[3] = f_to_bf_rne(sa[3]);
        o8[4] = f_to_bf_rne(sb[0]); o8[5] = f_to_bf_rne(sb[1]);
        o8[6] = f_to_bf_rne(sb[2]); o8[7] = f_to_bf_rne(sb[3]);
        acc8[(size_t)node * 16 + q] = o8;
        v4f ra = bf4_to_f((v4u){o8[0], o8[1], o8[2], o8[3]});   // stats on rounded y
        v4f rb = bf4_to_f((v4u){o8[4], o8[5], o8[6], o8[7]});
        t1a += ra; t1b += rb;
        t2a += ra * ra; t2b += rb * rb;
    }

    __shared__ float sh1[16][HD];
    __shared__ float sh2[16][HD];
    *(v4f*)&sh1[n][q * 8] = t1a;
    *(v4f*)&sh1[n][q * 8 + 4] = t1b;
    *(v4f*)&sh2[n][q * 8] = t2a;
    *(v4f*)&sh2[n][q * 8 + 4] = t2b;
    __syncthreads();
    if (threadIdx.x < HD) {
        int c = threadIdx.x;
        float a1 = 0.f, a2 = 0.f;
#pragma unroll
        for (int i = 0; i < 16; ++i) { a1 += sh1[i][c]; a2 += sh2[i][c]; }
        atomicAdd(&colsum[c], a1);
        atomicAdd(&colsumsq[c], a2);
    }
}

__global__ void bn_finalize(const float* __restrict__ colsum, const float* __restrict__ colsumsq,
                            const float* __restrict__ gamma, const float* __restrict__ beta,
                            float* __restrict__ scale, float* __restrict__ shift) {
    int c = threadIdx.x;
    float invn = 1.0f / (float)NN;
    float m = colsum[c] * invn;
    float v = colsumsq[c] * invn - m * m;
    float sc = gamma[c] * rsqrtf(v + BN_EPS);
    scale[c] = sc;
    shift[c] = beta[c] - m * sc;
}

// gstart[g] = first node index with batch >= g (batch is sorted ascending).
__global__ void group_bounds(const int* __restrict__ batch, int* __restrict__ gstart) {
    int g = blockIdx.x * blockDim.x + threadIdx.x;
    if (g > NG) return;
    if (g == NG) { gstart[NG] = NN; return; }
    int lo = 0, hi = NN;
    while (lo < hi) {
        int mid = (lo + hi) >> 1;
        if (batch[mid] < g) lo = mid + 1; else hi = mid;
    }
    gstart[g] = lo;
}

// Fused last-layer bn_apply + mean-pool: pool[g][c] = mean(h + relu(y*scale+shift)).
__launch_bounds__(128)
__global__ void pool_bn_mean(const unsigned short* __restrict__ acc,
                             const unsigned short* __restrict__ h,
                             const float* __restrict__ scale, const float* __restrict__ shift,
                             const int* __restrict__ gstart, float* __restrict__ pool) {
    int g = blockIdx.x;
    int c = threadIdx.x;
    float sc = scale[c], sf = shift[c];
    int s = gstart[g], e = gstart[g + 1];
    float a = 0.f;
    for (int r = s; r < e; ++r) {
        float yv = bf_to_f(acc[(size_t)r * HD + c]);
        float y = fmaxf(fmaf(yv, sc, sf), 0.f);
        a += bf_to_f(h[(size_t)r * HD + c]) + y;
    }
    float ic = 1.0f / fmaxf((float)(e - s), 1.0f);
    pool[(size_t)g * HD + c] = a * ic;
}

__launch_bounds__(128)
__global__ void out_gemm(const float* __restrict__ pool,
                         const float* __restrict__ Wout, const float* __restrict__ bout,
                         float* __restrict__ out) {
    __shared__ float hb[HD];
    int g = blockIdx.x;
    int c = threadIdx.x;
    hb[c] = pool[(size_t)g * HD + c];
    __syncthreads();
    float o = bout[c];
#pragma unroll 8
    for (int k = 0; k < HD; ++k) o = fmaf(hb[k], Wout[k * HD + c], o);
    out[(size_t)g * HD + c] = o;
}

extern "C" void kernel_launch(void* const* d_in, const int* in_sizes, int n_in,
                              void* d_out, int out_size, void* d_ws, size_t ws_size,
                              hipStream_t stream) {
    const float* x      = (const float*)d_in[0];
    const float* W_in   = (const float*)d_in[1];
    const float* b_in   = (const float*)d_in[2];
    const float* W_conv = (const float*)d_in[3];
    // d_in[4] = b_conv — cancels exactly inside BatchNorm (mean shift only), unused.
    const float* gamma  = (const float*)d_in[5];
    const float* beta   = (const float*)d_in[6];
    const float* W_out  = (const float*)d_in[7];
    const float* b_out  = (const float*)d_in[8];
    const int*   edge   = (const int*)d_in[9];
    const int*   batch  = (const int*)d_in[10];
    float* out = (float*)d_out;

    char* ws = (char*)d_ws;
    float* dinv   = (float*)(ws + OFF_DINV);
    unsigned short* h   = (unsigned short*)(ws + OFF_H);
    unsigned short* u   = (unsigned short*)(ws + OFF_U);
    unsigned short* acc = (unsigned short*)(ws + OFF_ACC);
    float* pool   = (float*)(ws + OFF_POOL);
    int*   gstart = (int*)(ws + OFF_GSTART);
    float* csum   = (float*)(ws + OFF_CSUM);
    float* csq    = (float*)(ws + OFF_CSQ);
    float* scale  = (float*)(ws + OFF_SCALE);
    float* shift  = (float*)(ws + OFF_SHIFT);
    int*   cnti   = (int*)(ws + OFF_CNTI);
    int*   offs   = (int*)(ws + OFF_OFFS);
    int*   cur    = (int*)(ws + OFF_CUR);
    int*   srcs   = (int*)(ws + OFF_SRCS);
    int*   bsum   = (int*)(ws + OFF_BSUM);

    const int* row = edge;        // sources
    const int* col = edge + NE;   // targets

    // zero: BN stats region, and cnti/cur region
    hipMemsetAsync(ws + OFF_CSUM, 0, OFF_SHIFT + 512 - OFF_CSUM, stream);
    hipMemsetAsync(ws + OFF_CNTI, 0, OFF_SRCS - OFF_CNTI, stream);

    // CSR build + dinv + group bounds
    count_deg_i<<<(NE + 255) / 256, 256, 0, stream>>>(col, cnti);
    finalize_dinv<<<(NN + 255) / 256, 256, 0, stream>>>(cnti, dinv);
    scan_phase1<<<SCAN_B, 256, 0, stream>>>(cnti, bsum);
    scan_phase2<<<1, 64, 0, stream>>>(bsum, offs);
    scan_phase3<<<SCAN_B, 256, 0, stream>>>(cnti, bsum, offs);
    fill_csr<<<(NE + 255) / 256, 256, 0, stream>>>(row, col, offs, cur, srcs);
    group_bounds<<<(NG + 256) / 256, 256, 0, stream>>>(batch, gstart);

    // h = bf16(x @ W_in + b_in)   (A fp32 -> 3-term split)
    gemm_mfma<true, false, false, false><<<GEMM_BLOCKS, 512, 0, stream>>>(
        (void*)x, W_in, b_in, nullptr, nullptr, nullptr, nullptr, h, NN);

    for (int l = 0; l < NL; ++l) {
        // u = bf16((h @ W_conv[l]) * dinv); for l>0 the A-load fuses the
        // previous layer's bn_apply (h = bf16(h + relu(acc*scale+shift)), in place).
        if (l == 0) {
            gemm_mfma<false, true, false, true><<<GEMM_BLOCKS, 512, 0, stream>>>(
                h, W_conv + (size_t)l * HD * HD, nullptr, dinv,
                nullptr, nullptr, nullptr, u, NN);
        } else {
            gemm_mfma<false, true, true, true><<<GEMM_BLOCKS, 512, 0, stream>>>(
                h, W_conv + (size_t)l * HD * HD, nullptr, dinv,
                scale, shift, acc, u, NN);
        }
        gather_bn<<<GATHER_BLOCKS, 256, 0, stream>>>(
            offs, srcs, u, dinv, acc, csum + l * HD, csq + l * HD);
        bn_finalize<<<1, HD, 0, stream>>>(
            csum + l * HD, csq + l * HD, gamma + l * HD, beta + l * HD, scale, shift);
    }

    // fused: pool[g] = mean(h + relu(acc*scale+shift)) over group rows
    pool_bn_mean<<<NG, 128, 0, stream>>>(acc, h, scale, shift, gstart, pool);
    out_gemm<<<NG, 128, 0, stream>>>(pool, W_out, b_out, out);
}